// Round 4
// baseline (456.901 us; speedup 1.0000x reference)
//
#include <hip/hip_runtime.h>
#include <hip/hip_bf16.h>
#include <cstdint>

#define NN 8192
#define DIN 512
#define DOUT 128
#define NEG_SLOPE 0.2f
#define MAXE 256

typedef float fvec4 __attribute__((ext_vector_type(4)));

__device__ inline fvec4 ntload4(const float* p) {
#if __has_builtin(__builtin_nontemporal_load)
    return __builtin_nontemporal_load((const fvec4*)p);
#else
    return *(const fvec4*)p;
#endif
}

// ---------- Kernel 1: h = x @ W ; a_s = h@attn_self ; a_n = h@attn_neigh ----
// 512 blocks x 256 threads, 16 rows/block (2 blocks/CU, 8 waves/CU).
// Thread tile = 2 rows x 4 cols: c = tid&31 -> cols 4c..4c+3, rg = tid>>5 ->
// rows 2rg, 2rg+1. Each W float4 (coalesced, L1-shared across row-groups)
// feeds 2 rows; W L2 traffic = 512 blocks x 256 KB = 128 MB (was 2 GB).
// x tile in LDS; all lanes of a row-group read the same address (broadcast).
__global__ __launch_bounds__(256) void k_gemm_h(
    const float* __restrict__ x, const float* __restrict__ W,
    const float* __restrict__ attn_self, const float* __restrict__ attn_neigh,
    float* __restrict__ h, float* __restrict__ a_s, float* __restrict__ a_n) {
    __shared__ float4 xs[16 * 128];   // 16 rows x 512 floats = 32 KB
    const int tid = threadIdx.x;
    const int m0 = blockIdx.x * 16;
    const float4* x4 = (const float4*)(x + (size_t)m0 * DIN);
#pragma unroll
    for (int r = 0; r < 8; ++r) xs[tid + 256 * r] = x4[tid + 256 * r];
    __syncthreads();

    const int c = tid & 31;
    const int rg = tid >> 5;
    const float4* W4 = (const float4*)W;           // row k = 32 float4
    const float4* xra = xs + (2 * rg) * 128;
    const float4* xrb = xs + (2 * rg + 1) * 128;
    float4 acca = {0.f, 0.f, 0.f, 0.f};
    float4 accb = {0.f, 0.f, 0.f, 0.f};
#pragma unroll 4
    for (int k4 = 0; k4 < 128; ++k4) {
        float4 xa = xra[k4];
        float4 xb = xrb[k4];
        float4 w0 = W4[(4 * k4 + 0) * 32 + c];
        float4 w1 = W4[(4 * k4 + 1) * 32 + c];
        float4 w2 = W4[(4 * k4 + 2) * 32 + c];
        float4 w3 = W4[(4 * k4 + 3) * 32 + c];
        acca.x += xa.x * w0.x + xa.y * w1.x + xa.z * w2.x + xa.w * w3.x;
        acca.y += xa.x * w0.y + xa.y * w1.y + xa.z * w2.y + xa.w * w3.y;
        acca.z += xa.x * w0.z + xa.y * w1.z + xa.z * w2.z + xa.w * w3.z;
        acca.w += xa.x * w0.w + xa.y * w1.w + xa.z * w2.w + xa.w * w3.w;
        accb.x += xb.x * w0.x + xb.y * w1.x + xb.z * w2.x + xb.w * w3.x;
        accb.y += xb.x * w0.y + xb.y * w1.y + xb.z * w2.y + xb.w * w3.y;
        accb.z += xb.x * w0.z + xb.y * w1.z + xb.z * w2.z + xb.w * w3.z;
        accb.w += xb.x * w0.w + xb.y * w1.w + xb.z * w2.w + xb.w * w3.w;
    }

    float4 as4 = ((const float4*)attn_self)[c];
    float4 an4 = ((const float4*)attn_neigh)[c];
    const int rowa = m0 + 2 * rg;
    ((float4*)h)[(size_t)rowa * 32 + c] = acca;
    ((float4*)h)[(size_t)(rowa + 1) * 32 + c] = accb;

    float psa = acca.x * as4.x + acca.y * as4.y + acca.z * as4.z + acca.w * as4.w;
    float pna = acca.x * an4.x + acca.y * an4.y + acca.z * an4.z + acca.w * an4.w;
    float psb = accb.x * as4.x + accb.y * as4.y + accb.z * as4.z + accb.w * as4.w;
    float pnb = accb.x * an4.x + accb.y * an4.y + accb.z * an4.z + accb.w * an4.w;
#pragma unroll
    for (int off = 16; off > 0; off >>= 1) {
        psa += __shfl_xor(psa, off);
        pna += __shfl_xor(pna, off);
        psb += __shfl_xor(psb, off);
        pnb += __shfl_xor(pnb, off);
    }
    if (c == 0) {
        a_s[rowa] = psa; a_n[rowa] = pna;
        a_s[rowa + 1] = psb; a_n[rowa + 1] = pnb;
    }
}

// ---------- Kernel 2: per-row sparse attention ----------
// One block (256 thr) per row i. Single pass: scan adj row (nontemporal
// float4, coalesced), compute leaky logit inline for each edge, LDS edge
// list, softmax over edges, weighted gather of h, relu.
__global__ __launch_bounds__(256) void k_attn(
    const float* __restrict__ adj, const float* __restrict__ h,
    const float* __restrict__ a_s, const float* __restrict__ a_n,
    float* __restrict__ out) {
    const int i = blockIdx.x;
    const int tid = threadIdx.x;
    __shared__ int s_cnt;
    __shared__ int s_idx[MAXE];
    __shared__ float s_w[MAXE];     // logits, then exp weights in-place
    __shared__ float s_red[4];
    __shared__ float s_red2[4];
    __shared__ float s_acc[256];
    if (tid == 0) s_cnt = 0;
    const float asi = a_s[i];
    __syncthreads();

    // --- scan + inline logits ---
    const float* arow = adj + ((size_t)i << 13);
    fvec4 v[8];
#pragma unroll
    for (int r = 0; r < 8; ++r) v[r] = ntload4(arow + 4 * (tid + 256 * r));
#pragma unroll
    for (int r = 0; r < 8; ++r) {
        int base = (tid + 256 * r) * 4;
#pragma unroll
        for (int q = 0; q < 4; ++q) {
            if (v[r][q] != 0.f) {
                int j = base + q;
                float e = asi + a_n[j];
                e = (e >= 0.f) ? e : NEG_SLOPE * e;
                int p = atomicAdd(&s_cnt, 1);
                if (p < MAXE) { s_idx[p] = j; s_w[p] = e; }
            }
        }
    }
    __syncthreads();
    const int cnt = min(s_cnt, MAXE);   // >=1 (self-loop)

    // --- max ---
    float m = -1e30f;
    for (int t = tid; t < cnt; t += 256) m = fmaxf(m, s_w[t]);
#pragma unroll
    for (int off = 32; off > 0; off >>= 1) m = fmaxf(m, __shfl_xor(m, off));
    if ((tid & 63) == 0) s_red[tid >> 6] = m;
    __syncthreads();
    m = fmaxf(fmaxf(s_red[0], s_red[1]), fmaxf(s_red[2], s_red[3]));

    // --- exp + sum (in-place) ---
    float lsum = 0.f;
    for (int t = tid; t < cnt; t += 256) {
        float w = __expf(s_w[t] - m);
        s_w[t] = w;
        lsum += w;
    }
#pragma unroll
    for (int off = 32; off > 0; off >>= 1) lsum += __shfl_xor(lsum, off);
    if ((tid & 63) == 0) s_red2[tid >> 6] = lsum;
    __syncthreads();
    const float inv_d = 1.0f / (s_red2[0] + s_red2[1] + s_red2[2] + s_red2[3]);

    // --- weighted gather: col c = tid&127, edges interleaved over 2 halves,
    //     4 loads in flight per thread ---
    const int c = tid & 127;
    const int half = tid >> 7;
    float acc = 0.f;
    int t = half;
    for (; t + 6 < cnt; t += 8) {
        float w0 = s_w[t];     int j0 = s_idx[t];
        float w1 = s_w[t + 2]; int j1 = s_idx[t + 2];
        float w2 = s_w[t + 4]; int j2 = s_idx[t + 4];
        float w3 = s_w[t + 6]; int j3 = s_idx[t + 6];
        float h0 = h[(size_t)j0 * DOUT + c];
        float h1 = h[(size_t)j1 * DOUT + c];
        float h2 = h[(size_t)j2 * DOUT + c];
        float h3 = h[(size_t)j3 * DOUT + c];
        acc += w0 * h0 + w1 * h1 + w2 * h2 + w3 * h3;
    }
    for (; t < cnt; t += 2) acc += s_w[t] * h[(size_t)s_idx[t] * DOUT + c];

    s_acc[tid] = acc;
    __syncthreads();
    if (tid < 128) {
        float tot = (s_acc[tid] + s_acc[tid + 128]) * inv_d;
        out[(size_t)i * DOUT + tid] = fmaxf(tot, 0.f);
    }
}

extern "C" void kernel_launch(void* const* d_in, const int* in_sizes, int n_in,
                              void* d_out, int out_size, void* d_ws, size_t ws_size,
                              hipStream_t stream) {
    const float* x          = (const float*)d_in[0];
    const float* adj        = (const float*)d_in[1];
    const float* W          = (const float*)d_in[2];
    const float* attn_self  = (const float*)d_in[3];
    const float* attn_neigh = (const float*)d_in[4];
    float* out = (float*)d_out;

    // workspace layout (floats): h[8192*128] | a_s[8192] | a_n[8192]
    float* h   = (float*)d_ws;
    float* a_s = h + (size_t)NN * DOUT;
    float* a_n = a_s + NN;

    hipLaunchKernelGGL(k_gemm_h, dim3(NN / 16), dim3(256), 0, stream,
                       x, W, attn_self, attn_neigh, h, a_s, a_n);
    hipLaunchKernelGGL(k_attn, dim3(NN), dim3(256), 0, stream, adj, h, a_s, a_n, out);
}

// Round 5
// 415.353 us; speedup vs baseline: 1.1000x; 1.1000x over previous
//
#include <hip/hip_runtime.h>
#include <hip/hip_bf16.h>
#include <cstdint>

#define NN 8192
#define DIN 512
#define DOUT 128
#define NEG_SLOPE 0.2f
#define MAXE 256
#define GEMM_BLOCKS 1024

typedef float fvec4 __attribute__((ext_vector_type(4)));

__device__ inline fvec4 ntload4(const float* p) {
#if __has_builtin(__builtin_nontemporal_load)
    return __builtin_nontemporal_load((const fvec4*)p);
#else
    return *(const fvec4*)p;
#endif
}

// ---------- Kernel 1 (fused, block-specialized) ----------
// Blocks 0..1023: GEMM h = x@W (8 rows/block, R3's measured-best config:
//   latency-bound loop wants 16 waves/CU) + a_s/a_n epilogue.
// Blocks 1024..9215: adj row scan -> compacted edge list in ws.
// The two paths share no data; scan is HBM-stream-bound, GEMM is VALU/L1 --
// they co-schedule on different pipes (m114), hiding the GEMM entirely.
__global__ __launch_bounds__(256) void k_fused(
    const float* __restrict__ x, const float* __restrict__ W,
    const float* __restrict__ attn_self, const float* __restrict__ attn_neigh,
    const float* __restrict__ adj,
    float* __restrict__ h, float* __restrict__ a_s, float* __restrict__ a_n,
    int* __restrict__ e_cnt, int* __restrict__ e_idx) {
    __shared__ char smem_raw[16384];
    __shared__ int s_cnt;
    const int tid = threadIdx.x;
    const int bid = blockIdx.x;

    if (bid < GEMM_BLOCKS) {
        // ---- GEMM path (identical to R3 k_gemm_h) ----
        float4* xs = (float4*)smem_raw;          // 8 rows x 512 floats = 16 KB
        const int m0 = bid * 8;
        const float4* x4 = (const float4*)(x + (size_t)m0 * DIN);
#pragma unroll
        for (int r = 0; r < 4; ++r) xs[tid + 256 * r] = x4[tid + 256 * r];
        __syncthreads();

        const int c4 = tid & 31;
        const int rg = tid >> 5;
        const float4* W4 = (const float4*)W;      // row k = 32 float4
        const float4* xr = xs + rg * 128;
        float4 acc = {0.f, 0.f, 0.f, 0.f};
#pragma unroll 4
        for (int k4 = 0; k4 < 128; ++k4) {
            float4 xv = xr[k4];
            float4 w0 = W4[(4 * k4 + 0) * 32 + c4];
            float4 w1 = W4[(4 * k4 + 1) * 32 + c4];
            float4 w2 = W4[(4 * k4 + 2) * 32 + c4];
            float4 w3 = W4[(4 * k4 + 3) * 32 + c4];
            acc.x += xv.x * w0.x + xv.y * w1.x + xv.z * w2.x + xv.w * w3.x;
            acc.y += xv.x * w0.y + xv.y * w1.y + xv.z * w2.y + xv.w * w3.y;
            acc.z += xv.x * w0.z + xv.y * w1.z + xv.z * w2.z + xv.w * w3.z;
            acc.w += xv.x * w0.w + xv.y * w1.w + xv.z * w2.w + xv.w * w3.w;
        }
        const int row = m0 + rg;
        ((float4*)h)[(size_t)row * 32 + c4] = acc;

        float4 as4 = ((const float4*)attn_self)[c4];
        float4 an4 = ((const float4*)attn_neigh)[c4];
        float ps = acc.x * as4.x + acc.y * as4.y + acc.z * as4.z + acc.w * as4.w;
        float pn = acc.x * an4.x + acc.y * an4.y + acc.z * an4.z + acc.w * an4.w;
#pragma unroll
        for (int off = 16; off > 0; off >>= 1) {
            ps += __shfl_xor(ps, off);
            pn += __shfl_xor(pn, off);
        }
        if (c4 == 0) { a_s[row] = ps; a_n[row] = pn; }
    } else {
        // ---- adj scan path: compact row i's edges into ws ----
        const int i = bid - GEMM_BLOCKS;
        int* s_idx = (int*)smem_raw;             // MAXE ints = 1 KB
        if (tid == 0) s_cnt = 0;
        __syncthreads();

        const float* arow = adj + ((size_t)i << 13);
        fvec4 v[8];
#pragma unroll
        for (int r = 0; r < 8; ++r) v[r] = ntload4(arow + 4 * (tid + 256 * r));
#pragma unroll
        for (int r = 0; r < 8; ++r) {
            int base = (tid + 256 * r) * 4;
#pragma unroll
            for (int q = 0; q < 4; ++q) {
                if (v[r][q] != 0.f) {
                    int p = atomicAdd(&s_cnt, 1);
                    if (p < MAXE) s_idx[p] = base + q;
                }
            }
        }
        __syncthreads();
        const int cnt = min(s_cnt, MAXE);        // >=1 (self-loop)
        for (int t = tid; t < cnt; t += 256) e_idx[(size_t)i * MAXE + t] = s_idx[t];
        if (tid == 0) e_cnt[i] = cnt;
    }
}

// ---------- Kernel 2: logits + softmax + weighted gather ----------
// One block per row. Everything except the 4 MB out-write is L2/L3-hit
// (edge lists ~1 MB, a_n 32 KB, h 4 MB).
__global__ __launch_bounds__(256) void k_soft(
    const float* __restrict__ h, const float* __restrict__ a_s,
    const float* __restrict__ a_n, const int* __restrict__ e_cnt,
    const int* __restrict__ e_idx, float* __restrict__ out) {
    const int i = blockIdx.x;
    const int tid = threadIdx.x;
    __shared__ int s_idx[MAXE];
    __shared__ float s_w[MAXE];
    __shared__ float s_red[4];
    __shared__ float s_red2[4];
    __shared__ float s_acc[256];

    const int cnt = e_cnt[i];
    const float asi = a_s[i];

    // logits + running max
    float m = -1e30f;
    for (int t = tid; t < cnt; t += 256) {
        int j = e_idx[(size_t)i * MAXE + t];
        s_idx[t] = j;
        float e = asi + a_n[j];
        e = (e >= 0.f) ? e : NEG_SLOPE * e;
        s_w[t] = e;
        m = fmaxf(m, e);
    }
#pragma unroll
    for (int off = 32; off > 0; off >>= 1) m = fmaxf(m, __shfl_xor(m, off));
    if ((tid & 63) == 0) s_red[tid >> 6] = m;
    __syncthreads();
    m = fmaxf(fmaxf(s_red[0], s_red[1]), fmaxf(s_red[2], s_red[3]));

    // exp + sum (in-place)
    float lsum = 0.f;
    for (int t = tid; t < cnt; t += 256) {
        float w = __expf(s_w[t] - m);
        s_w[t] = w;
        lsum += w;
    }
#pragma unroll
    for (int off = 32; off > 0; off >>= 1) lsum += __shfl_xor(lsum, off);
    if ((tid & 63) == 0) s_red2[tid >> 6] = lsum;
    __syncthreads();
    const float inv_d = 1.0f / (s_red2[0] + s_red2[1] + s_red2[2] + s_red2[3]);

    // weighted gather: col c = tid&127, edges interleaved over 2 halves
    const int c = tid & 127;
    const int half = tid >> 7;
    float acc = 0.f;
    int t = half;
    for (; t + 6 < cnt; t += 8) {
        float w0 = s_w[t];     int j0 = s_idx[t];
        float w1 = s_w[t + 2]; int j1 = s_idx[t + 2];
        float w2 = s_w[t + 4]; int j2 = s_idx[t + 4];
        float w3 = s_w[t + 6]; int j3 = s_idx[t + 6];
        float h0 = h[(size_t)j0 * DOUT + c];
        float h1 = h[(size_t)j1 * DOUT + c];
        float h2 = h[(size_t)j2 * DOUT + c];
        float h3 = h[(size_t)j3 * DOUT + c];
        acc += w0 * h0 + w1 * h1 + w2 * h2 + w3 * h3;
    }
    for (; t < cnt; t += 2) acc += s_w[t] * h[(size_t)s_idx[t] * DOUT + c];

    s_acc[tid] = acc;
    __syncthreads();
    if (tid < 128) {
        float tot = (s_acc[tid] + s_acc[tid + 128]) * inv_d;
        out[(size_t)i * DOUT + tid] = fmaxf(tot, 0.f);
    }
}

extern "C" void kernel_launch(void* const* d_in, const int* in_sizes, int n_in,
                              void* d_out, int out_size, void* d_ws, size_t ws_size,
                              hipStream_t stream) {
    const float* x          = (const float*)d_in[0];
    const float* adj        = (const float*)d_in[1];
    const float* W          = (const float*)d_in[2];
    const float* attn_self  = (const float*)d_in[3];
    const float* attn_neigh = (const float*)d_in[4];
    float* out = (float*)d_out;

    // ws layout: h[8192*128] | a_s[8192] | a_n[8192] | e_cnt[8192] | e_idx[8192*MAXE]
    float* h   = (float*)d_ws;
    float* a_s = h + (size_t)NN * DOUT;
    float* a_n = a_s + NN;
    int* e_cnt = (int*)(a_n + NN);
    int* e_idx = e_cnt + NN;

    hipLaunchKernelGGL(k_fused, dim3(GEMM_BLOCKS + NN), dim3(256), 0, stream,
                       x, W, attn_self, attn_neigh, adj, h, a_s, a_n, e_cnt, e_idx);
    hipLaunchKernelGGL(k_soft, dim3(NN), dim3(256), 0, stream,
                       h, a_s, a_n, e_cnt, e_idx, out);
}